// Round 6
// baseline (483.341 us; speedup 1.0000x reference)
//
#include <hip/hip_runtime.h>

#define NDET 50000
#define DEG 32
#define NEDGE (NDET * DEG)
#define NGROUP (NEDGE / 64)   // 25000 groups of 2 dets / 64 edges

typedef __attribute__((ext_vector_type(8))) short short8;
typedef __attribute__((ext_vector_type(4))) float f32x4;

__device__ inline unsigned short f2bf(float x) {
    return (unsigned short)((__builtin_bit_cast(unsigned int, x) + 0x8000u) >> 16);
}

__device__ inline short8 pack8(f32x4 a, f32x4 b) {
    short8 r;
    r[0] = (short)f2bf(a[0]); r[1] = (short)f2bf(a[1]);
    r[2] = (short)f2bf(a[2]); r[3] = (short)f2bf(a[3]);
    r[4] = (short)f2bf(b[0]); r[5] = (short)f2bf(b[1]);
    r[6] = (short)f2bf(b[2]); r[7] = (short)f2bf(b[3]);
    return r;
}

// non-temporal (streaming) loads: keep L2 free for the hbf gather table.
// NOTE: __builtin_nontemporal_load requires a clang ext_vector (not HIP_vector_type).
__device__ inline f32x4 nt4(const float* p) {
    return __builtin_nontemporal_load((const f32x4*)p);
}
__device__ inline int ntI(const int* p) { return __builtin_nontemporal_load(p); }
__device__ inline float ntF(const float* p) { return __builtin_nontemporal_load(p); }

// ---------------------------------------------------------------------------
// Kernel A: hbf = bf16(relu(detF @ W_fc1 + b_fc1))  via MFMA, K=128.
// ---------------------------------------------------------------------------
__global__ __launch_bounds__(256, 4) void fc1_kernel(
    const float* __restrict__ detF,     // [NDET][128]
    const float* __restrict__ W,        // [128][32]
    const float* __restrict__ b,        // [32]
    unsigned short* __restrict__ hbf)   // [NDET][32] bf16
{
    __shared__ __align__(16) unsigned short WT[32 * 136];

    const int tid  = threadIdx.x;
    const int lane = tid & 63;
    const int wv   = tid >> 6;
    const int m16  = lane & 15;
    const int q    = lane >> 4;

    for (int i = tid; i < 32 * 128; i += 256) {
        int n = i >> 7, k = i & 127;
        WT[n * 136 + k] = f2bf(W[k * 32 + n]);
    }
    __syncthreads();

    const int g = blockIdx.x * 4 + wv;
    if (g >= (NDET + 63) / 64) return;
    const int d0 = g * 64;

    f32x4 acc[4][2];
#pragma unroll
    for (int nt = 0; nt < 2; nt++) {
        float c0 = b[nt * 16 + m16];
#pragma unroll
        for (int mt = 0; mt < 4; mt++) acc[mt][nt] = (f32x4){c0, c0, c0, c0};
    }

#pragma unroll
    for (int ks = 0; ks < 4; ks++) {
#pragma unroll
        for (int mt = 0; mt < 4; mt++) {
            int row = d0 + mt * 16 + m16;
            if (row >= NDET) row = NDET - 1;
            const float* pr = detF + (size_t)row * 128 + ks * 32 + q * 8;
            short8 a = pack8(nt4(pr), nt4(pr + 4));
#pragma unroll
            for (int nt = 0; nt < 2; nt++) {
                short8 bf = *(const short8*)&WT[(nt * 16 + m16) * 136 + ks * 32 + q * 8];
                acc[mt][nt] = __builtin_amdgcn_mfma_f32_16x16x32_bf16(a, bf, acc[mt][nt], 0, 0, 0);
            }
        }
    }

#pragma unroll
    for (int mt = 0; mt < 4; mt++)
#pragma unroll
        for (int r = 0; r < 4; r++) {
            int row = d0 + mt * 16 + q * 4 + r;
            if (row < NDET) {
#pragma unroll
                for (int nt = 0; nt < 2; nt++)
                    hbf[(size_t)row * 32 + nt * 16 + m16] = f2bf(fmaxf(acc[mt][nt][r], 0.0f));
            }
        }
}

// ---------------------------------------------------------------------------
// Kernel B: edge MLP. nt-loads for streams; split-depth pipeline:
// nIdx prefetched 2 iters ahead, gather/pairF/center 1 iter ahead.
// ---------------------------------------------------------------------------
__global__ __launch_bounds__(256, 3) void edge_kernel(
    const unsigned short* __restrict__ hbf,   // [NDET][32] bf16
    const int* __restrict__ nIdx,             // [NEDGE]
    const float* __restrict__ pairF,          // [NEDGE][32] fp32
    const float* __restrict__ W1,             // [96][64]
    const float* __restrict__ b1,
    const float* __restrict__ W2,             // [64][64]
    const float* __restrict__ b2,
    unsigned short* __restrict__ m_bf)        // [NDET][64] bf16
{
    __shared__ __align__(16) unsigned short Y1s[4][64 * 72];  // 36864 B (also W1 staging)
    __shared__ __align__(16) unsigned short W2T[64 * 72];     // 9216 B, persistent

    const int tid  = threadIdx.x;
    const int lane = tid & 63;
    const int wv   = tid >> 6;
    const int m16  = lane & 15;
    const int q    = lane >> 4;

    unsigned short* st = &Y1s[0][0];
    for (int i = tid; i < 64 * 96; i += 256) {
        int n = i / 96, k = i - n * 96;
        st[i] = f2bf(W1[k * 64 + n]);
    }
    for (int i = tid; i < 64 * 64; i += 256) {
        int n = i >> 6, k = i & 63;
        W2T[n * 72 + k] = f2bf(W2[k * 64 + n]);
    }
    __syncthreads();

    short8 w1f[3][4];
#pragma unroll
    for (int nt = 0; nt < 4; nt++) {
        const unsigned short* base = &st[(nt * 16 + m16) * 96];
        w1f[0][nt] = *(const short8*)&base[q * 8];        // pair rows 0..31
        w1f[1][nt] = *(const short8*)&base[64 + q * 8];   // nbr rows 64..95
        w1f[2][nt] = *(const short8*)&base[32 + q * 8];   // center rows 32..63
    }
    float b1r[4], b2r[4];
#pragma unroll
    for (int nt = 0; nt < 4; nt++) {
        b1r[nt] = b1[nt * 16 + m16];
        b2r[nt] = b2[nt * 16 + m16];
    }
    __syncthreads();   // staging -> per-wave Y1 tiles

    unsigned short* Y1w = &Y1s[wv][0];

    const int wstride = (int)gridDim.x * 4;
    int g = blockIdx.x * 4 + wv;
    if (g >= NGROUP) return;

    int    ni_cur[4], ni_next[4];
    f32x4  pv[4][2];
    short8 nb[4];
    short8 cf2[2];
    const short8 zr = {0, 0, 0, 0, 0, 0, 0, 0};

    // ---- prologue: fill pipeline for group g, nIdx also for g+w ----
    {
        const int E0 = g * 64, d0 = g * 2;
#pragma unroll
        for (int mt = 0; mt < 4; mt++)
            ni_cur[mt] = ntI(&nIdx[E0 + mt * 16 + m16]);
#pragma unroll
        for (int mt = 0; mt < 4; mt++) {
            const float* pr = pairF + (size_t)(E0 + mt * 16 + m16) * 32 + q * 8;
            pv[mt][0] = nt4(pr);
            pv[mt][1] = nt4(pr + 4);
        }
#pragma unroll
        for (int mt = 0; mt < 4; mt++)
            nb[mt] = *(const short8*)&hbf[(size_t)ni_cur[mt] * 32 + q * 8];
        cf2[0] = *(const short8*)&hbf[(size_t)d0 * 32 + q * 8];
        cf2[1] = *(const short8*)&hbf[(size_t)(d0 + 1) * 32 + q * 8];
        const int g1 = g + wstride;
        const int gs = (g1 < NGROUP) ? g1 : g;
#pragma unroll
        for (int mt = 0; mt < 4; mt++)
            ni_next[mt] = ntI(&nIdx[gs * 64 + mt * 16 + m16]);
    }

    while (true) {
        const int d0 = g * 2;
        // ---- consume pipeline into A-frags ----
        short8 ap[4], an[4], ac[4];
#pragma unroll
        for (int mt = 0; mt < 4; mt++) {
            ap[mt] = pack8(pv[mt][0], pv[mt][1]);
            an[mt] = (ni_cur[mt] == d0 + (mt >> 1)) ? zr : nb[mt];
            ac[mt] = cf2[mt >> 1];
        }

        const int g1 = g + wstride;
        const bool more = (g1 < NGROUP);
        const int gn = more ? g1 : g;           // next group (dead = self)
        const int g2 = g1 + wstride;
        const int gf = (g2 < NGROUP) ? g2 : gn; // far group for nIdx

        // ---- issue prefetches: nIdx depth-2, rest depth-1 ----
        int ni_far[4];
#pragma unroll
        for (int mt = 0; mt < 4; mt++)
            ni_far[mt] = ntI(&nIdx[gf * 64 + mt * 16 + m16]);
#pragma unroll
        for (int mt = 0; mt < 4; mt++) {
            const float* pr = pairF + (size_t)(gn * 64 + mt * 16 + m16) * 32 + q * 8;
            pv[mt][0] = nt4(pr);
            pv[mt][1] = nt4(pr + 4);
            nb[mt] = *(const short8*)&hbf[(size_t)ni_next[mt] * 32 + q * 8];
        }
        cf2[0] = *(const short8*)&hbf[(size_t)(gn * 2) * 32 + q * 8];
        cf2[1] = *(const short8*)&hbf[(size_t)(gn * 2 + 1) * 32 + q * 8];

        // ---- MLP1: K=96, 48 MFMA ----
        f32x4 acc[4][4];
#pragma unroll
        for (int mt = 0; mt < 4; mt++)
#pragma unroll
            for (int nt = 0; nt < 4; nt++) {
                float c0 = b1r[nt];
                acc[mt][nt] = (f32x4){c0, c0, c0, c0};
            }
#pragma unroll
        for (int mt = 0; mt < 4; mt++)
#pragma unroll
            for (int nt = 0; nt < 4; nt++) {
                acc[mt][nt] = __builtin_amdgcn_mfma_f32_16x16x32_bf16(ap[mt], w1f[0][nt], acc[mt][nt], 0, 0, 0);
                acc[mt][nt] = __builtin_amdgcn_mfma_f32_16x16x32_bf16(an[mt], w1f[1][nt], acc[mt][nt], 0, 0, 0);
                acc[mt][nt] = __builtin_amdgcn_mfma_f32_16x16x32_bf16(ac[mt], w1f[2][nt], acc[mt][nt], 0, 0, 0);
            }

        // ---- Y1 = relu -> bf16 -> LDS ----
#pragma unroll
        for (int mt = 0; mt < 4; mt++)
#pragma unroll
            for (int nt = 0; nt < 4; nt++)
#pragma unroll
                for (int r = 0; r < 4; r++)
                    Y1w[(mt * 16 + q * 4 + r) * 72 + nt * 16 + m16] =
                        f2bf(fmaxf(acc[mt][nt][r], 0.0f));

        // ---- MLP2: K=64, 32 MFMA ----
        f32x4 acc2[4][4];
#pragma unroll
        for (int mt = 0; mt < 4; mt++)
#pragma unroll
            for (int nt = 0; nt < 4; nt++) {
                float c0 = b2r[nt];
                acc2[mt][nt] = (f32x4){c0, c0, c0, c0};
            }
#pragma unroll
        for (int ks = 0; ks < 2; ks++) {
            short8 af[4];
#pragma unroll
            for (int mt = 0; mt < 4; mt++)
                af[mt] = *(const short8*)&Y1w[(mt * 16 + m16) * 72 + ks * 32 + q * 8];
#pragma unroll
            for (int nt = 0; nt < 4; nt++) {
                short8 wf = *(const short8*)&W2T[(nt * 16 + m16) * 72 + ks * 32 + q * 8];
#pragma unroll
                for (int mt = 0; mt < 4; mt++)
                    acc2[mt][nt] = __builtin_amdgcn_mfma_f32_16x16x32_bf16(af[mt], wf, acc2[mt][nt], 0, 0, 0);
            }
        }

        // ---- relu + per-det max + bf16 store ----
#pragma unroll
        for (int d = 0; d < 2; d++)
#pragma unroll
            for (int nt = 0; nt < 4; nt++) {
                float v = 0.0f;
#pragma unroll
                for (int mt = 2 * d; mt < 2 * d + 2; mt++)
#pragma unroll
                    for (int r = 0; r < 4; r++) v = fmaxf(v, acc2[mt][nt][r]);
                v = fmaxf(v, __shfl_xor(v, 16));
                v = fmaxf(v, __shfl_xor(v, 32));
                if (q == 0) m_bf[(size_t)(d0 + d) * 64 + nt * 16 + m16] = f2bf(v);
            }

        if (!more) break;
#pragma unroll
        for (int mt = 0; mt < 4; mt++) {
            ni_cur[mt]  = ni_next[mt];
            ni_next[mt] = ni_far[mt];
        }
        g = g1;
    }
}

// ---------------------------------------------------------------------------
// Kernel C: tail via MFMA (nt loads for detF).
// ---------------------------------------------------------------------------
__global__ __launch_bounds__(256, 2) void tail_kernel(
    const float* __restrict__ detF,
    const unsigned short* __restrict__ m_bf,   // [NDET][64] bf16
    const float* __restrict__ Wm1, const float* __restrict__ bm1,
    const float* __restrict__ Wm2, const float* __restrict__ bm2,
    const float* __restrict__ Wo,  const float* __restrict__ bo,
    float* __restrict__ out)
{
    __shared__ __align__(16) unsigned short W1T[64 * 72];
    __shared__ __align__(16) unsigned short W2T[64 * 72];
    __shared__ __align__(16) unsigned short WoT[128 * 72];
    __shared__ __align__(16) unsigned short Tt[4][64 * 72];

    const int tid  = threadIdx.x;
    const int lane = tid & 63;
    const int wv   = tid >> 6;
    const int m16  = lane & 15;
    const int q    = lane >> 4;

    for (int i = tid; i < 64 * 64; i += 256) {
        int n = i >> 6, k = i & 63;
        W1T[n * 72 + k] = f2bf(Wm1[k * 64 + n]);
        W2T[n * 72 + k] = f2bf(Wm2[k * 64 + n]);
    }
    for (int i = tid; i < 128 * 64; i += 256) {
        int n = i >> 6, k = i & 63;
        WoT[n * 72 + k] = f2bf(Wo[k * 128 + n]);
    }
    __syncthreads();

    float bm1r[4], bm2r[4], bor[8];
#pragma unroll
    for (int nt = 0; nt < 4; nt++) {
        bm1r[nt] = bm1[nt * 16 + m16];
        bm2r[nt] = bm2[nt * 16 + m16];
    }
#pragma unroll
    for (int nt = 0; nt < 8; nt++) bor[nt] = bo[nt * 16 + m16];

    unsigned short* Tw = &Tt[wv][0];
    const int NTG = (NDET + 63) / 64;

    for (int gI = blockIdx.x * 4 + wv; gI < NTG; gI += (int)gridDim.x * 4) {
        const int d0 = gI * 64;

        f32x4 acc[4][4];
#pragma unroll
        for (int mt = 0; mt < 4; mt++)
#pragma unroll
            for (int nt = 0; nt < 4; nt++) {
                float c0 = bm1r[nt];
                acc[mt][nt] = (f32x4){c0, c0, c0, c0};
            }
#pragma unroll
        for (int ks = 0; ks < 2; ks++) {
            short8 af[4];
#pragma unroll
            for (int mt = 0; mt < 4; mt++) {
                int row = d0 + mt * 16 + m16;
                if (row >= NDET) row = NDET - 1;
                af[mt] = *(const short8*)&m_bf[(size_t)row * 64 + ks * 32 + q * 8];
            }
#pragma unroll
            for (int mt = 0; mt < 4; mt++)
#pragma unroll
                for (int nt = 0; nt < 4; nt++) {
                    short8 bf = *(const short8*)&W1T[(nt * 16 + m16) * 72 + ks * 32 + q * 8];
                    acc[mt][nt] = __builtin_amdgcn_mfma_f32_16x16x32_bf16(af[mt], bf, acc[mt][nt], 0, 0, 0);
                }
        }
#pragma unroll
        for (int mt = 0; mt < 4; mt++)
#pragma unroll
            for (int nt = 0; nt < 4; nt++)
#pragma unroll
                for (int r = 0; r < 4; r++)
                    Tw[(mt * 16 + q * 4 + r) * 72 + nt * 16 + m16] =
                        f2bf(fmaxf(acc[mt][nt][r], 0.0f));

#pragma unroll
        for (int mt = 0; mt < 4; mt++)
#pragma unroll
            for (int nt = 0; nt < 4; nt++) {
                float c0 = bm2r[nt];
                acc[mt][nt] = (f32x4){c0, c0, c0, c0};
            }
#pragma unroll
        for (int ks = 0; ks < 2; ks++) {
            short8 af[4];
#pragma unroll
            for (int mt = 0; mt < 4; mt++)
                af[mt] = *(const short8*)&Tw[(mt * 16 + m16) * 72 + ks * 32 + q * 8];
#pragma unroll
            for (int mt = 0; mt < 4; mt++)
#pragma unroll
                for (int nt = 0; nt < 4; nt++) {
                    short8 bf = *(const short8*)&W2T[(nt * 16 + m16) * 72 + ks * 32 + q * 8];
                    acc[mt][nt] = __builtin_amdgcn_mfma_f32_16x16x32_bf16(af[mt], bf, acc[mt][nt], 0, 0, 0);
                }
        }
#pragma unroll
        for (int mt = 0; mt < 4; mt++)
#pragma unroll
            for (int nt = 0; nt < 4; nt++)
#pragma unroll
                for (int r = 0; r < 4; r++)
                    Tw[(mt * 16 + q * 4 + r) * 72 + nt * 16 + m16] =
                        f2bf(fmaxf(acc[mt][nt][r], 0.0f));

        short8 a3[4][2];
#pragma unroll
        for (int ks = 0; ks < 2; ks++)
#pragma unroll
            for (int mt = 0; mt < 4; mt++)
                a3[mt][ks] = *(const short8*)&Tw[(mt * 16 + m16) * 72 + ks * 32 + q * 8];

#pragma unroll
        for (int h2 = 0; h2 < 2; h2++) {
            f32x4 acc3[4][4];
#pragma unroll
            for (int mt = 0; mt < 4; mt++)
#pragma unroll
                for (int nt = 0; nt < 4; nt++) {
                    float c0 = bor[h2 * 4 + nt];
                    acc3[mt][nt] = (f32x4){c0, c0, c0, c0};
                }
#pragma unroll
            for (int ks = 0; ks < 2; ks++)
#pragma unroll
                for (int mt = 0; mt < 4; mt++)
#pragma unroll
                    for (int nt = 0; nt < 4; nt++) {
                        short8 bf = *(const short8*)&WoT[((h2 * 4 + nt) * 16 + m16) * 72 + ks * 32 + q * 8];
                        acc3[mt][nt] = __builtin_amdgcn_mfma_f32_16x16x32_bf16(a3[mt][ks], bf, acc3[mt][nt], 0, 0, 0);
                    }
#pragma unroll
            for (int mt = 0; mt < 4; mt++)
#pragma unroll
                for (int r = 0; r < 4; r++) {
                    int row = d0 + mt * 16 + q * 4 + r;
                    if (row < NDET) {
#pragma unroll
                        for (int nt = 0; nt < 4; nt++) {
                            int col = (h2 * 4 + nt) * 16 + m16;
                            float v = ntF(&detF[(size_t)row * 128 + col]) + acc3[mt][nt][r];
                            out[(size_t)row * 128 + col] = fmaxf(v, 0.0f);
                        }
                    }
                }
        }
    }
}

// ---------------------------------------------------------------------------
extern "C" void kernel_launch(void* const* d_in, const int* in_sizes, int n_in,
                              void* d_out, int out_size, void* d_ws, size_t ws_size,
                              hipStream_t stream)
{
    const float* detF  = (const float*)d_in[0];
    const int*   nIdx  = (const int*)d_in[2];
    const float* pairF = (const float*)d_in[3];
    const float* W_fc1 = (const float*)d_in[4];
    const float* b_fc1 = (const float*)d_in[5];
    const float* W_pw1 = (const float*)d_in[6];
    const float* b_pw1 = (const float*)d_in[7];
    const float* W_pw2 = (const float*)d_in[8];
    const float* b_pw2 = (const float*)d_in[9];
    const float* W_pm1 = (const float*)d_in[10];
    const float* b_pm1 = (const float*)d_in[11];
    const float* W_pm2 = (const float*)d_in[12];
    const float* b_pm2 = (const float*)d_in[13];
    const float* W_out = (const float*)d_in[14];
    const float* b_out = (const float*)d_in[15];
    float* out = (float*)d_out;

    unsigned short* hbf  = (unsigned short*)d_ws;          // [NDET][32] bf16
    unsigned short* m_bf = hbf + (size_t)NDET * 32;        // [NDET][64] bf16

    fc1_kernel<<<(NDET + 255) / 256, 256, 0, stream>>>(detF, W_fc1, b_fc1, hbf);
    edge_kernel<<<768, 256, 0, stream>>>(hbf, nIdx, pairF,
                                         W_pw1, b_pw1, W_pw2, b_pw2, m_bf);
    tail_kernel<<<256, 256, 0, stream>>>(detF, m_bf, W_pm1, b_pm1, W_pm2, b_pm2,
                                         W_out, b_out, out);
}